// Round 1
// baseline (122.190 us; speedup 1.0000x reference)
//
#include <hip/hip_runtime.h>

// Gaussian-kernel MMD loss, N=M=8192, D=2.
// loss = mean(k_bb) + mean(k_tt) - 2*mean(k_bt), k = exp(-||x-y||^2 / (2 sigma^2))
// Centering only affects the cross term (as a shift by mean_b - mean_t).

struct Params {
    float scale0, scale1;   // exp(log_scale)
    float shift0, shift1;   // mean_b - mean_t (of scaled points)
    float c;                // -inv2s2 * log2(e)  (for exp2)
};

__device__ __forceinline__ float fexp2(float x) {
#if defined(__has_builtin)
#if __has_builtin(__builtin_amdgcn_exp2f)
    return __builtin_amdgcn_exp2f(x);
#else
    return exp2f(x);
#endif
#else
    return exp2f(x);
#endif
}

// ---------------- prep: scales, means, constants ----------------
__global__ void prep_kernel(const float* __restrict__ base,
                            const float* __restrict__ target,
                            const float* __restrict__ log_sigma,
                            const float* __restrict__ log_scale,
                            int N, int M,
                            double* __restrict__ acc,     // 3 doubles (zeroed here)
                            Params* __restrict__ pp)
{
    const int tid = threadIdx.x;
    if (tid < 3) acc[tid] = 0.0;

    double sb0 = 0.0, sb1 = 0.0, st0 = 0.0, st1 = 0.0;
    for (int i = tid; i < N; i += blockDim.x) {
        sb0 += (double)base[2 * i];
        sb1 += (double)base[2 * i + 1];
    }
    for (int i = tid; i < M; i += blockDim.x) {
        st0 += (double)target[2 * i];
        st1 += (double)target[2 * i + 1];
    }
    // wave reduce (64 lanes)
    for (int off = 32; off; off >>= 1) {
        sb0 += __shfl_down(sb0, off);
        sb1 += __shfl_down(sb1, off);
        st0 += __shfl_down(st0, off);
        st1 += __shfl_down(st1, off);
    }
    __shared__ double wred[4][4];
    const int wid = tid >> 6, lane = tid & 63;
    if (lane == 0) {
        wred[wid][0] = sb0; wred[wid][1] = sb1;
        wred[wid][2] = st0; wred[wid][3] = st1;
    }
    __syncthreads();
    if (tid == 0) {
        double b0 = 0, b1 = 0, t0 = 0, t1 = 0;
        const int nw = (blockDim.x + 63) >> 6;
        for (int w = 0; w < nw; ++w) {
            b0 += wred[w][0]; b1 += wred[w][1];
            t0 += wred[w][2]; t1 += wred[w][3];
        }
        float s0 = expf(log_scale[0]);
        float s1 = expf(log_scale[1]);
        double mb0 = (double)s0 * b0 / (double)N;
        double mb1 = (double)s1 * b1 / (double)N;
        double mt0 = (double)s0 * t0 / (double)M;
        double mt1 = (double)s1 * t1 / (double)M;
        float sigma = expf(log_sigma[0]);
        float inv2s2 = 1.0f / (2.0f * sigma * sigma);
        double c = -(double)inv2s2 * 1.4426950408889634; // * log2(e)
        pp->scale0 = s0; pp->scale1 = s1;
        pp->shift0 = (float)(mb0 - mt0);
        pp->shift1 = (float)(mb1 - mt1);
        pp->c = (float)c;
    }
}

// ---------------- main pairwise kernel ----------------
#define BLOCK 256
#define JTILE 1024

__global__ __launch_bounds__(BLOCK) void pair_kernel(
    const float* __restrict__ base, const float* __restrict__ target,
    int N, int M,
    const Params* __restrict__ pp, double* __restrict__ acc)
{
    __shared__ float2 tb[JTILE];
    __shared__ double wred[BLOCK / 64];

    const int term = blockIdx.z;
    const Params p = *pp;

    const float* A; const float* B; int NA, NB;
    float sh0 = 0.0f, sh1 = 0.0f;
    if (term == 0)      { A = base;   B = base;   NA = N; NB = N; }
    else if (term == 1) { A = target; B = target; NA = M; NB = M; }
    else                { A = base;   B = target; NA = N; NB = M;
                          sh0 = p.shift0; sh1 = p.shift1; }

    const int j0 = blockIdx.y * JTILE;
    const int jn = min(JTILE, NB - j0);   // may be <= 0 for uneven terms

    for (int j = threadIdx.x; j < jn; j += BLOCK) {
        // fold scale and (for cross term) +shift into the B tile:
        // diff = a_scaled - (b_scaled + (mean_b - mean_t))
        float bx = B[2 * (j0 + j)]     * p.scale0 + sh0;
        float by = B[2 * (j0 + j) + 1] * p.scale1 + sh1;
        tb[j] = make_float2(bx, by);
    }
    __syncthreads();

    const int r = blockIdx.x * BLOCK + threadIdx.x;
    double accd = 0.0;
    if (r < NA && jn > 0) {
        const float ax = A[2 * r]     * p.scale0;
        const float ay = A[2 * r + 1] * p.scale1;
        const float c = p.c;
        for (int jj = 0; jj < jn; jj += 256) {
            const int je = min(jj + 256, jn);
            float accf = 0.0f;
            int j = jj;
            for (; j + 8 <= je; j += 8) {
#pragma unroll
                for (int u = 0; u < 8; ++u) {
                    float2 b = tb[j + u];          // wave-uniform addr -> LDS broadcast
                    float dx = ax - b.x;
                    float dy = ay - b.y;
                    float d2 = fmaf(dy, dy, dx * dx);
                    accf += fexp2(c * d2);
                }
            }
            for (; j < je; ++j) {
                float2 b = tb[j];
                float dx = ax - b.x;
                float dy = ay - b.y;
                float d2 = fmaf(dy, dy, dx * dx);
                accf += fexp2(c * d2);
            }
            accd += (double)accf;                  // flush every <=256 terms
        }
    }

    // block reduction (all threads participate)
    for (int off = 32; off; off >>= 1) accd += __shfl_down(accd, off);
    const int wid = threadIdx.x >> 6, lane = threadIdx.x & 63;
    if (lane == 0) wred[wid] = accd;
    __syncthreads();
    if (threadIdx.x == 0) {
        double s = 0.0;
        for (int w = 0; w < BLOCK / 64; ++w) s += wred[w];
        atomicAdd(&acc[term], s);
    }
}

// ---------------- finalize ----------------
__global__ void final_kernel(const double* __restrict__ acc, int N, int M,
                             float* __restrict__ out)
{
    double invN = 1.0 / (double)N, invM = 1.0 / (double)M;
    double loss = acc[0] * invN * invN
                + acc[1] * invM * invM
                - 2.0 * acc[2] * invN * invM;
    out[0] = (float)loss;
}

extern "C" void kernel_launch(void* const* d_in, const int* in_sizes, int n_in,
                              void* d_out, int out_size, void* d_ws, size_t ws_size,
                              hipStream_t stream)
{
    const float* base      = (const float*)d_in[0];
    const float* target    = (const float*)d_in[1];
    const float* log_sigma = (const float*)d_in[2];
    const float* log_scale = (const float*)d_in[3];
    float* out = (float*)d_out;

    const int N = in_sizes[0] / 2;
    const int M = in_sizes[1] / 2;

    double* acc = (double*)d_ws;                       // 3 accumulators
    Params* pp  = (Params*)((char*)d_ws + 64);

    prep_kernel<<<1, 256, 0, stream>>>(base, target, log_sigma, log_scale,
                                       N, M, acc, pp);

    const int maxR = (N > M) ? N : M;
    dim3 grid((maxR + BLOCK - 1) / BLOCK,
              (maxR + JTILE - 1) / JTILE,
              3);
    pair_kernel<<<grid, dim3(BLOCK), 0, stream>>>(base, target, N, M, pp, acc);

    final_kernel<<<1, 1, 0, stream>>>(acc, N, M, out);
}

// Round 2
// 100.200 us; speedup vs baseline: 1.2195x; 1.2195x over previous
//
#include <hip/hip_runtime.h>

// Gaussian-kernel MMD loss, N=M=8192, D=2.
// loss = mean(k_bb) + mean(k_tt) - 2*mean(k_bt), k = exp(-||x-y||^2/(2 s^2))
// - Centering only affects the cross term (shift B by mean_b - mean_t).
// - k_bb/k_tt symmetric: upper-triangle tiles only, off-diag weighted 2x.
// - Coords pre-scaled by scale_k * sqrt(inv2s2*log2(e)) so inner loop is
//   sub,sub,mul,fma,exp2(-d2),add  (5 VALU + 1 trans per pair).

#define BLOCK 256
#define TILE  256
#define LOG2E 1.4426950408889634f

__device__ __forceinline__ float fexp2(float x) {
    return __builtin_amdgcn_exp2f(x);
}

__global__ __launch_bounds__(BLOCK) void mmd_kernel(
    const float* __restrict__ base, const float* __restrict__ target,
    const float* __restrict__ log_sigma, const float* __restrict__ log_scale,
    int N, int M, double* __restrict__ acc)
{
    __shared__ float2 tb[TILE];
    __shared__ double wred[BLOCK / 64];
    __shared__ double mred[BLOCK / 64][4];
    __shared__ float2 shsh;

    const int term = blockIdx.z;
    const int ib = blockIdx.x, jb = blockIdx.y;
    const int tid = threadIdx.x;

    const float* A; const float* B; int NA, NB;
    if (term == 0)      { A = base;   B = base;   NA = N; NB = N; }
    else if (term == 1) { A = target; B = target; NA = M; NB = M; }
    else                { A = base;   B = target; NA = N; NB = M; }

    const int i0 = ib * TILE, j0 = jb * TILE;
    if (i0 >= NA || j0 >= NB) return;
    if (term < 2 && jb < ib) return;          // symmetric: upper triangle only

    // uniform constants (every thread computes; values are wave-uniform)
    const float s0    = expf(log_scale[0]);
    const float s1    = expf(log_scale[1]);
    const float sigma = expf(log_sigma[0]);
    const float inv2s2 = 1.0f / (2.0f * sigma * sigma);
    const float sq = sqrtf(inv2s2 * LOG2E);
    const float f0 = s0 * sq, f1 = s1 * sq;

    // cross term: shift = mean_b - mean_t in the pre-scaled space.
    // Computed redundantly per term-2 block (inputs are tiny, L2-resident).
    float sh0 = 0.0f, sh1 = 0.0f;
    if (term == 2) {
        double sb0 = 0, sb1 = 0, st0 = 0, st1 = 0;
        const float4* b4 = (const float4*)base;
        const float4* t4 = (const float4*)target;
        for (int i = tid; i < (N >> 1); i += BLOCK) {
            float4 v = b4[i];
            sb0 += (double)v.x + (double)v.z;
            sb1 += (double)v.y + (double)v.w;
        }
        for (int i = tid; i < (M >> 1); i += BLOCK) {
            float4 v = t4[i];
            st0 += (double)v.x + (double)v.z;
            st1 += (double)v.y + (double)v.w;
        }
        for (int off = 32; off; off >>= 1) {
            sb0 += __shfl_down(sb0, off); sb1 += __shfl_down(sb1, off);
            st0 += __shfl_down(st0, off); st1 += __shfl_down(st1, off);
        }
        const int w = tid >> 6;
        if ((tid & 63) == 0) {
            mred[w][0] = sb0; mred[w][1] = sb1;
            mred[w][2] = st0; mred[w][3] = st1;
        }
        __syncthreads();
        if (tid == 0) {
            double b0 = 0, b1 = 0, t0 = 0, t1 = 0;
            for (int k = 0; k < BLOCK / 64; ++k) {
                b0 += mred[k][0]; b1 += mred[k][1];
                t0 += mred[k][2]; t1 += mred[k][3];
            }
            shsh.x = (float)(b0 / N - t0 / M) * f0;
            shsh.y = (float)(b1 / N - t1 / M) * f1;
        }
        __syncthreads();
        sh0 = shsh.x; sh1 = shsh.y;
    }

    // stage B tile into LDS, scale+shift folded in:
    // diff = a*f - (b*f + shift)
    const int jn = min(TILE, NB - j0);
    if (tid < jn) {
        float2 b = ((const float2*)B)[j0 + tid];
        tb[tid] = make_float2(fmaf(b.x, f0, sh0), fmaf(b.y, f1, sh1));
    }
    __syncthreads();

    const int r = i0 + tid;
    double accd = 0.0;
    if (r < NA) {
        float2 a = ((const float2*)A)[r];
        const float ax = a.x * f0, ay = a.y * f1;
        float acc0 = 0, acc1 = 0, acc2 = 0, acc3 = 0;
        if (jn == TILE) {
#pragma unroll 2
            for (int j = 0; j < TILE; j += 4) {
                float4 p01 = *(const float4*)&tb[j];
                float4 p23 = *(const float4*)&tb[j + 2];
                float dx0 = ax - p01.x, dy0 = ay - p01.y;
                float dx1 = ax - p01.z, dy1 = ay - p01.w;
                float dx2 = ax - p23.x, dy2 = ay - p23.y;
                float dx3 = ax - p23.z, dy3 = ay - p23.w;
                float d0 = fmaf(dy0, dy0, dx0 * dx0);
                float d1 = fmaf(dy1, dy1, dx1 * dx1);
                float d2 = fmaf(dy2, dy2, dx2 * dx2);
                float d3 = fmaf(dy3, dy3, dx3 * dx3);
                acc0 += fexp2(-d0);
                acc1 += fexp2(-d1);
                acc2 += fexp2(-d2);
                acc3 += fexp2(-d3);
            }
        } else {
            for (int j = 0; j < jn; ++j) {
                float2 p = tb[j];
                float dx = ax - p.x, dy = ay - p.y;
                float d = fmaf(dy, dy, dx * dx);
                acc0 += fexp2(-d);
            }
        }
        accd = (double)((acc0 + acc1) + (acc2 + acc3));
    }

    // block reduction (all threads participate; inactive rows contribute 0)
    for (int off = 32; off; off >>= 1) accd += __shfl_down(accd, off);
    if ((tid & 63) == 0) wred[tid >> 6] = accd;
    __syncthreads();
    if (tid == 0) {
        double s = 0.0;
        for (int w = 0; w < BLOCK / 64; ++w) s += wred[w];
        if (term < 2 && jb != ib) s *= 2.0;   // symmetric off-diagonal tile
        atomicAdd(&acc[term], s);
    }
}

__global__ void final_kernel(const double* __restrict__ acc, int N, int M,
                             float* __restrict__ out)
{
    double invN = 1.0 / (double)N, invM = 1.0 / (double)M;
    double loss = acc[0] * invN * invN
                + acc[1] * invM * invM
                - 2.0 * acc[2] * invN * invM;
    out[0] = (float)loss;
}

extern "C" void kernel_launch(void* const* d_in, const int* in_sizes, int n_in,
                              void* d_out, int out_size, void* d_ws, size_t ws_size,
                              hipStream_t stream)
{
    const float* base      = (const float*)d_in[0];
    const float* target    = (const float*)d_in[1];
    const float* log_sigma = (const float*)d_in[2];
    const float* log_scale = (const float*)d_in[3];
    float* out = (float*)d_out;

    const int N = in_sizes[0] / 2;
    const int M = in_sizes[1] / 2;

    double* acc = (double*)d_ws;   // 3 accumulators
    hipMemsetAsync(acc, 0, 3 * sizeof(double), stream);

    const int tmax = (((N > M) ? N : M) + TILE - 1) / TILE;
    dim3 grid(tmax, tmax, 3);
    mmd_kernel<<<grid, dim3(BLOCK), 0, stream>>>(base, target, log_sigma,
                                                 log_scale, N, M, acc);
    final_kernel<<<1, 1, 0, stream>>>(acc, N, M, out);
}